// Round 7
// baseline (125.136 us; speedup 1.0000x reference)
//
#include <hip/hip_runtime.h>

typedef _Float16 f16;
typedef f16 f16x8 __attribute__((ext_vector_type(8)));
typedef f16 f16x4 __attribute__((ext_vector_type(4)));
typedef float f32x4 __attribute__((ext_vector_type(4)));

// ---- LDS tile strides/offsets (units: f16 elements), 16x8-pixel tile ----
// x0: 11 rows x 24 cols (gy in [ty*8-1,  ty*8+10)),  stride 28
// x1: 20 rows x 44 cols (gy in [ty*16-2, ty*16+18)), stride 48
// x2: 40 rows x 88 cols (gy in [ty*32-4, ty*32+36)), stride 92
#define S0 28
#define S1 48
#define S2 92
#define T0OFF 0
#define T1OFF (11 * S0)                 // 308
#define T2OFF (T1OFF + 20 * S1)         // 1268
#define TILEH (T2OFF + 40 * S2)         // 4948 f16 = 9896 B
#define LOG2E 1.4426950408889634f

// K' = 256 layout (8 ksteps of 32):
//  kp in [0,16)   : layer0, ki=kp>>2, kj=kp&3   ; real iff ki<3 && kj<3 -> orig = 3*ki+kj
//  kp in [16,64)  : layer1, kk=kp-16, ki=kk>>3, kj=kk&7 ; real iff kj<6 -> orig = 9+6*ki+kj
//  kp in [64,256) : layer2, kk=kp-64, ki=kk>>4, kj=kk&15; real iff kj<12 -> orig = 45+12*ki+kj
//
// Fragment-major Wt in LDS: fragment f = (s*4 + t), slot f*512 + lane*8 holds
// the 8 f16 W-elements (k = s*32 + quad*8 + j, n = t*16 + ln).  Serves as the
// *A* operand (operand-swapped MFMA): A[m=ln][k=quad*8+j] = W[k][chan=t*16+ln].
//
// prep_wt is MERGED into fuse: each block gathers the 32 KB Wt from W (48 KB,
// L2/L3-hot after first touch) into LDS during the x2 HBM-latency window.
// This removes a serialized 8-block kernel + two launch boundaries per iter.
__global__ __launch_bounds__(256, 3) void fuse_kernel(
    const float* __restrict__ x0, const float* __restrict__ x1,
    const float* __restrict__ x2, const float* __restrict__ W,
    float* __restrict__ out)
{
  __shared__ __align__(16) f16 tiles[TILEH];
  __shared__ __align__(16) f16 wt[16384];     // 32 fragments * 512 f16 = 32 KB

  const int tid  = threadIdx.x;
  // bijective XCD swizzle: 2048 wgs = 8 XCDs x 256; XCD k owns images [8k, 8k+8)
  const int bid  = ((blockIdx.x & 7) << 8) | (blockIdx.x >> 3);
  const int nb   = bid >> 5;          // image
  const int ty   = (bid >> 2) & 3;    // 8-px tile row -- see note below
  // NOTE: bid layout: nb = bid>>5, rem = bid&31 -> ty = rem>>2 (0..7), tx = rem&3
  const int ty8  = (bid >> 2) & 7;    // 8-px tile row, 0..7
  const int tx   = bid & 3;           // 16-px tile col
  const int lane = tid & 63;
  const int wid  = tid >> 6;
  const int ln   = lane & 15;
  const int quad = lane >> 4;
  (void)ty;

  // ---- issue x2 loads first (biggest input, longest latency): 40 x 22 float4 = 880
  // 880 = 3*256 + 112 -> i=0..2 unconditional, i=3 predicated on tid<112.
  f32x4 v2[4];
  {
    const float* img = x2 + nb * 65536;
    #pragma unroll
    for (int i = 0; i < 4; ++i) {
      int idx = tid + 256 * i;
      int r  = idx / 22, c4 = idx - r * 22;
      int gy = ty8 * 32 - 4 + r;
      int gx = tx * 64 - 8 + 4 * c4;
      bool inb = (i < 3 || tid < 112) && ((unsigned)gy < 256u) && ((unsigned)gx < 256u);
      v2[i] = inb ? *(const f32x4*)(img + gy * 256 + gx) : (f32x4){0.f, 0.f, 0.f, 0.f};
    }
  }

  // ---- gather Wt into LDS (replaces prep_wt; overlaps x2 HBM latency) ----
  // thread handles fragment-lane g = tid + 256*i, i = 0..7 (2048 total)
  #pragma unroll
  for (int i = 0; i < 8; ++i) {
    int g = tid + 256 * i;
    int s = g >> 8, t = (g >> 6) & 3, l = g & 63;
    int q = l >> 4, lnw = l & 15;
    int n = t * 16 + lnw;
    f16 vals[8];
    #pragma unroll
    for (int j = 0; j < 8; ++j) {
      int kp = s * 32 + q * 8 + j;
      int orig = -1;
      if (kp < 16)      { int ki = kp >> 2, kj = kp & 3;                   if (ki < 3 && kj < 3) orig = 3*ki + kj; }
      else if (kp < 64) { int kk = kp - 16; int ki = kk >> 3, kj = kk & 7;  if (kj < 6)          orig = 9 + 6*ki + kj; }
      else              { int kk = kp - 64; int ki = kk >> 4, kj = kk & 15; if (kj < 12)         orig = 45 + 12*ki + kj; }
      vals[j] = (f16)((orig >= 0) ? W[orig * 64 + n] : 0.f);
    }
    *(f16x8*)&wt[g * 8] = *(const f16x8*)vals;
  }

  // ---- stage x1 (20 x 11 float4 = 220) and x0 (11 x 6 = 66) ----
  {
    const float* img = x1 + nb * 16384;
    int idx = tid;
    int r  = idx / 11, c4 = idx - r * 11;
    int gy = ty8 * 16 - 2 + r;
    int gx = tx * 32 - 4 + 4 * c4;
    bool inb = (idx < 220) && ((unsigned)gy < 128u) && ((unsigned)gx < 128u);
    f32x4 t = inb ? *(const f32x4*)(img + gy * 128 + gx) : (f32x4){0.f, 0.f, 0.f, 0.f};
    if (idx < 220) {
      f16x4 h; h[0] = (f16)t[0]; h[1] = (f16)t[1]; h[2] = (f16)t[2]; h[3] = (f16)t[3];
      *(f16x4*)&tiles[T1OFF + r * S1 + 4 * c4] = h;
    }
  }
  {
    const float* img = x0 + nb * 4096;
    int idx = tid;
    int r  = idx / 6, c4 = idx - r * 6;
    int gy = ty8 * 8 - 1 + r;
    int gx = tx * 16 - 4 + 4 * c4;
    bool inb = (idx < 66) && ((unsigned)gy < 64u) && ((unsigned)gx < 64u);
    f32x4 t = inb ? *(const f32x4*)(img + gy * 64 + gx) : (f32x4){0.f, 0.f, 0.f, 0.f};
    if (idx < 66) {
      f16x4 h; h[0] = (f16)t[0]; h[1] = (f16)t[1]; h[2] = (f16)t[2]; h[3] = (f16)t[3];
      *(f16x4*)&tiles[T0OFF + r * S0 + 4 * c4] = h;
    }
  }

  // x0 scale pixels for the epilogue (exact f32); lane's pixel is (ty8*8+wid*2+cc, tx*16+ln)
  float xs[2];
  #pragma unroll
  for (int cc = 0; cc < 2; ++cc)
    xs[cc] = x0[nb * 4096 + (ty8 * 8 + wid * 2 + cc) * 64 + tx * 16 + ln];

  // ---- x2 -> LDS (the barrier's vmcnt(0) drain means data is here anyway) ----
  #pragma unroll
  for (int i = 0; i < 4; ++i) {
    if (i < 3 || tid < 112) {
      int idx = tid + 256 * i;
      int r  = idx / 22, c4 = idx - r * 22;
      f16x4 h; h[0] = (f16)v2[i][0]; h[1] = (f16)v2[i][1];
      h[2] = (f16)v2[i][2]; h[3] = (f16)v2[i][3];
      *(f16x4*)&tiles[T2OFF + r * S2 + 4 * c4] = h;
    }
  }

  __syncthreads();   // the ONLY barrier: tiles + Wt all ready

  const f16* wfrag = wt + lane * 8;

  f32x4 acc[2][4];
  #pragma unroll
  for (int c = 0; c < 2; ++c)
    #pragma unroll
    for (int t = 0; t < 4; ++t)
      acc[c][t] = (f32x4){0.f, 0.f, 0.f, 0.f};

  // ---- kstep 0: quads 0,1 -> layer0 ; quads 2,3 -> layer1 ----
  {
    f16x8 bf[4];
    #pragma unroll
    for (int t = 0; t < 4; ++t)
      bf[t] = *(const f16x8*)(wfrag + t * 512);
    #pragma unroll
    for (int cc = 0; cc < 2; ++cc) {
      const int py = wid * 2 + cc;
      f16x8 a;
      if (quad < 2) {
        // layer0: ki = 2*quad + (j>>2), kj = j&3; row = py+ki, col = ln+3+kj
        const int a0 = T0OFF + (py + 2 * quad) * S0 + ln + 3;
        #pragma unroll
        for (int j = 0; j < 4; ++j) a[j]     = tiles[a0 + j];
        #pragma unroll
        for (int j = 0; j < 4; ++j) a[4 + j] = tiles[a0 + S0 + j];
      } else {
        // layer1: ki = quad-2, kj = j; row = 2py+ki, col = 2ln+2+kj
        const int a1 = T1OFF + (2 * py + quad - 2) * S1 + 2 * ln + 2;
        #pragma unroll
        for (int j = 0; j < 8; ++j) a[j] = tiles[a1 + j];
      }
      #pragma unroll
      for (int t = 0; t < 4; ++t)
        acc[cc][t] = __builtin_amdgcn_mfma_f32_16x16x32_f16(bf[t], a, acc[cc][t], 0, 0, 0);
    }
  }
  // ---- kstep 1: all layer1, ki = 2+quad ----
  {
    f16x8 bf[4];
    #pragma unroll
    for (int t = 0; t < 4; ++t)
      bf[t] = *(const f16x8*)(wfrag + (4 + t) * 512);
    #pragma unroll
    for (int cc = 0; cc < 2; ++cc) {
      const int py = wid * 2 + cc;
      const int a1 = T1OFF + (2 * py + 2 + quad) * S1 + 2 * ln + 2;
      f16x8 a;
      #pragma unroll
      for (int j = 0; j < 8; ++j) a[j] = tiles[a1 + j];
      #pragma unroll
      for (int t = 0; t < 4; ++t)
        acc[cc][t] = __builtin_amdgcn_mfma_f32_16x16x32_f16(bf[t], a, acc[cc][t], 0, 0, 0);
    }
  }
  // ---- ksteps 2..7: layer2 ----
  // row = 4py + 2(s-2) + (quad>>1), col = 4ln + 4 + 8(quad&1) + j
  #pragma unroll 3
  for (int s = 2; s < 8; ++s) {
    f16x8 bf[4];
    #pragma unroll
    for (int t = 0; t < 4; ++t)
      bf[t] = *(const f16x8*)(wfrag + (s * 4 + t) * 512);
    #pragma unroll
    for (int cc = 0; cc < 2; ++cc) {
      const int py = wid * 2 + cc;
      const int b2 = T2OFF + (4 * py + 2 * (s - 2) + (quad >> 1)) * S2 + 4 * ln + 4 + 8 * (quad & 1);
      f16x4 lo = *(const f16x4*)&tiles[b2];
      f16x4 hi = *(const f16x4*)&tiles[b2 + 4];
      f16x8 a;
      a[0] = lo[0]; a[1] = lo[1]; a[2] = lo[2]; a[3] = lo[3];
      a[4] = hi[0]; a[5] = hi[1]; a[6] = hi[2]; a[7] = hi[3];
      #pragma unroll
      for (int t = 0; t < 4; ++t)
        acc[cc][t] = __builtin_amdgcn_mfma_f32_16x16x32_f16(bf[t], a, acc[cc][t], 0, 0, 0);
    }
  }

  // ---- epilogue: fully in-register softmax + direct coalesced stores ----
  const int gx8 = (tx * 16 + ln) * 8;
  #pragma unroll
  for (int cc = 0; cc < 2; ++cc) {
    float v[4][4];
    float m = 0.f;                       // logits are post-ReLU, so >= 0
    #pragma unroll
    for (int t = 0; t < 4; ++t)
      #pragma unroll
      for (int r = 0; r < 4; ++r) {
        float x = fmaxf(acc[cc][t][r], 0.f);
        v[t][r] = x;
        m = fmaxf(m, x);
      }
    m = fmaxf(m, __shfl_xor(m, 16));
    m = fmaxf(m, __shfl_xor(m, 32));

    float sden = 0.f;
    #pragma unroll
    for (int t = 0; t < 4; ++t)
      #pragma unroll
      for (int r = 0; r < 4; ++r) {
        float e = exp2f((v[t][r] - m) * LOG2E);
        v[t][r] = e;
        sden += e;
      }
    sden += __shfl_xor(sden, 16);
    sden += __shfl_xor(sden, 32);

    // rcp (1-ulp) instead of precise divide: absmax is f16-quantization bound.
    const float sc = xs[cc] * __builtin_amdgcn_rcpf(sden);
    const int gy = ty8 * 8 + wid * 2 + cc;
    // chan = 16t + 4*quad + r -> addr = (gy*8 + 2t + (quad>>1))*512 + gx*8 + 4*(quad&1) + r
    float* op = out + nb * 262144 + (gy * 8 + (quad >> 1)) * 512 + gx8 + 4 * (quad & 1);
    #pragma unroll
    for (int t = 0; t < 4; ++t) {
      f32x4 w;
      w[0] = v[t][0] * sc; w[1] = v[t][1] * sc;
      w[2] = v[t][2] * sc; w[3] = v[t][3] * sc;
      *(f32x4*)(op + t * 1024) = w;      // regular store: through L2
    }
  }
}

extern "C" void kernel_launch(void* const* d_in, const int* in_sizes, int n_in,
                              void* d_out, int out_size, void* d_ws, size_t ws_size,
                              hipStream_t stream) {
  const float* x0 = (const float*)d_in[0];
  const float* x1 = (const float*)d_in[1];
  const float* x2 = (const float*)d_in[2];
  const float* W  = (const float*)d_in[3];
  float* outp     = (float*)d_out;

  fuse_kernel<<<dim3(2048), dim3(256), 0, stream>>>(x0, x1, x2, W, outp);
}

// Round 8
// 106.871 us; speedup vs baseline: 1.1709x; 1.1709x over previous
//
#include <hip/hip_runtime.h>

typedef _Float16 f16;
typedef f16 f16x8 __attribute__((ext_vector_type(8)));
typedef f16 f16x4 __attribute__((ext_vector_type(4)));
typedef float f32x4 __attribute__((ext_vector_type(4)));

// ---- per-WAVE LDS slice (units: f16), wave wid owns pixel rows {2wid, 2wid+1} ----
// x0: 5 rows x 24 cols, stride 28 (gy = ty*8-1  + 2wid + rr, rr in [0,5))
// x1: 8 rows x 44 cols, stride 48 (gy = ty*16-2 + 4wid + rr, rr in [0,8))
// x2: 16 rows x 88 cols, stride 92 (gy = ty*32-4 + 8wid + rr, rr in [0,16))
// slice = 5*28 + 8*48 + 16*92 = 1996 f16, padded to 2048 (4 KB). 4 waves = 16 KB.
// NO cross-wave LDS sharing -> NO __syncthreads anywhere: each wave waits only
// on its own loads (compiler vmcnt/lgkmcnt), killing the block-wide barrier
// convoy where 1024 threads stall on the block's slowest staging load.
#define X0OFF 0
#define X1OFF 140
#define X2OFF 524
#define WSL   2048
#define LOG2E 1.4426950408889634f

// K' = 256 layout (8 ksteps of 32):
//  kp in [0,16)   : layer0, ki=kp>>2, kj=kp&3   ; real iff ki<3 && kj<3 -> orig = 3*ki+kj
//  kp in [16,64)  : layer1, kk=kp-16, ki=kk>>3, kj=kk&7 ; real iff kj<6 -> orig = 9+6*ki+kj
//  kp in [64,256) : layer2, kk=kp-64, ki=kk>>4, kj=kk&15; real iff kj<12 -> orig = 45+12*ki+kj
//
// Fragment-major storage: fragment f = (s*4 + t)*64 + lane holds the 8 f16
// W-elements (k = s*32 + quad*8 + j, n = t*16 + ln) -> every wave load is
// 64 lanes x 16 B CONTIGUOUS (1 KB).  Serves as the *A* operand
// (operand-swapped MFMA): A[m=ln][k=quad*8+j] = W[k][chan=t*16+ln].
__global__ void prep_wt(const float* __restrict__ W, f16* __restrict__ Wt) {
  const int f = blockIdx.x * 256 + threadIdx.x;   // 0..2047
  const int s = f >> 8;
  const int t = (f >> 6) & 3;
  const int lane = f & 63;
  const int quad = lane >> 4, ln = lane & 15;
  const int n = t * 16 + ln;
  f16 vals[8];
  #pragma unroll
  for (int j = 0; j < 8; ++j) {
    int kp = s * 32 + quad * 8 + j;
    int orig = -1;
    if (kp < 16)      { int ki = kp >> 2, kj = kp & 3;                   if (ki < 3 && kj < 3) orig = 3*ki + kj; }
    else if (kp < 64) { int kk = kp - 16; int ki = kk >> 3, kj = kk & 7;  if (kj < 6)          orig = 9 + 6*ki + kj; }
    else              { int kk = kp - 64; int ki = kk >> 4, kj = kk & 15; if (kj < 12)         orig = 45 + 12*ki + kj; }
    vals[j] = (f16)((orig >= 0) ? W[orig * 64 + n] : 0.f);
  }
  *(f16x8*)(Wt + (size_t)f * 8) = *(const f16x8*)vals;
}

// Operand-swapped MFMA: D = W_frag * patch_frag, so D col = lane&15 = pixel-x,
// D row = 4*quad + r = channel-in-group.  chan = 16t + 4*quad + r.
// Softmax over 64 channels of one pixel = 16 in-lane values + shfl_xor(16,32).
// Wave-autonomous: zero barriers in the whole kernel.
__global__ __launch_bounds__(256, 6) void fuse_kernel(
    const float* __restrict__ x0, const float* __restrict__ x1,
    const float* __restrict__ x2, const f16* __restrict__ Wt,
    float* __restrict__ out)
{
  __shared__ __align__(16) f16 tiles[4 * WSL];

  const int tid  = threadIdx.x;
  // bijective XCD swizzle: 2048 wgs = 8 XCDs x 256; XCD k owns images [8k, 8k+8)
  const int bid  = ((blockIdx.x & 7) << 8) | (blockIdx.x >> 3);
  const int nb   = bid >> 5;          // image
  const int ty8  = (bid >> 2) & 7;    // 8-px tile row
  const int tx   = bid & 3;           // 16-px tile col
  const int lane = tid & 63;
  const int wid  = tid >> 6;
  const int ln   = lane & 15;
  const int quad = lane >> 4;

  f16* sl = tiles + wid * WSL;        // this wave's private slice
  const f16* __restrict__ wfrag = Wt + (size_t)lane * 8;

  // ---- issue x2 loads first (longest latency): 16 rows x 22 f32x4 = 352 = 5*64+32
  f32x4 v2[6];
  {
    const float* img = x2 + nb * 65536;
    #pragma unroll
    for (int i = 0; i < 6; ++i) {
      int idx = lane + 64 * i;
      int rr = idx / 22, c4 = idx - rr * 22;
      int gy = ty8 * 32 - 4 + 8 * wid + rr;
      int gx = tx * 64 - 8 + 4 * c4;
      bool inb = (i < 5 || lane < 32) && ((unsigned)gy < 256u) && ((unsigned)gx < 256u);
      v2[i] = inb ? *(const f32x4*)(img + gy * 256 + gx) : (f32x4){0.f, 0.f, 0.f, 0.f};
    }
  }

  // ---- stage x1 (8 rows x 11 f32x4 = 88 = 64+24) and x0 (5 x 6 = 30) ----
  {
    const float* img = x1 + nb * 16384;
    #pragma unroll
    for (int i = 0; i < 2; ++i) {
      int idx = lane + 64 * i;
      int rr = idx / 11, c4 = idx - rr * 11;
      int gy = ty8 * 16 - 2 + 4 * wid + rr;
      int gx = tx * 32 - 4 + 4 * c4;
      bool ok  = (i < 1 || lane < 24);
      bool inb = ok && ((unsigned)gy < 128u) && ((unsigned)gx < 128u);
      f32x4 t = inb ? *(const f32x4*)(img + gy * 128 + gx) : (f32x4){0.f, 0.f, 0.f, 0.f};
      if (ok) {
        f16x4 h; h[0] = (f16)t[0]; h[1] = (f16)t[1]; h[2] = (f16)t[2]; h[3] = (f16)t[3];
        *(f16x4*)&sl[X1OFF + rr * 48 + 4 * c4] = h;
      }
    }
  }
  {
    const float* img = x0 + nb * 4096;
    int rr = lane / 6, c4 = lane - rr * 6;
    int gy = ty8 * 8 - 1 + 2 * wid + rr;
    int gx = tx * 16 - 4 + 4 * c4;
    bool ok  = lane < 30;
    bool inb = ok && ((unsigned)gy < 64u) && ((unsigned)gx < 64u);
    f32x4 t = inb ? *(const f32x4*)(img + gy * 64 + gx) : (f32x4){0.f, 0.f, 0.f, 0.f};
    if (ok) {
      f16x4 h; h[0] = (f16)t[0]; h[1] = (f16)t[1]; h[2] = (f16)t[2]; h[3] = (f16)t[3];
      *(f16x4*)&sl[X0OFF + rr * 28 + 4 * c4] = h;
    }
  }

  // x0 scale pixels for the epilogue (exact f32); lane's pixel is (ty8*8+2wid+cc, tx*16+ln)
  float xs[2];
  #pragma unroll
  for (int cc = 0; cc < 2; ++cc)
    xs[cc] = x0[nb * 4096 + (ty8 * 8 + 2 * wid + cc) * 64 + tx * 16 + ln];

  // ---- commit x2 to this wave's slice (vmcnt deps handled by compiler) ----
  #pragma unroll
  for (int i = 0; i < 6; ++i) {
    if (i < 5 || lane < 32) {
      int idx = lane + 64 * i;
      int rr = idx / 22, c4 = idx - rr * 22;
      f16x4 h; h[0] = (f16)v2[i][0]; h[1] = (f16)v2[i][1];
      h[2] = (f16)v2[i][2]; h[3] = (f16)v2[i][3];
      *(f16x4*)&sl[X2OFF + rr * 92 + 4 * c4] = h;
    }
  }

  // kstep-0 weight fragments (independent of LDS; overlaps the lgkm drain)
  f16x8 bf0[4];
  #pragma unroll
  for (int t = 0; t < 4; ++t)
    bf0[t] = *(const f16x8*)(wfrag + t * 512);

  // NO barrier: wave reads only its own slice; compiler inserts lgkmcnt waits.

  f32x4 acc[2][4];
  #pragma unroll
  for (int c = 0; c < 2; ++c)
    #pragma unroll
    for (int t = 0; t < 4; ++t)
      acc[c][t] = (f32x4){0.f, 0.f, 0.f, 0.f};

  // ---- kstep 0: quads 0,1 -> layer0 ; quads 2,3 -> layer1 ----
  // slice rows: layer0 rr = cc + 2*quad (+1); layer1 rr = 2cc + quad - 2
  {
    #pragma unroll
    for (int cc = 0; cc < 2; ++cc) {
      f16x8 a;
      if (quad < 2) {
        const int a0 = X0OFF + (cc + 2 * quad) * 28 + ln + 3;
        #pragma unroll
        for (int j = 0; j < 4; ++j) a[j]     = sl[a0 + j];
        #pragma unroll
        for (int j = 0; j < 4; ++j) a[4 + j] = sl[a0 + 28 + j];
      } else {
        const int a1 = X1OFF + (2 * cc + quad - 2) * 48 + 2 * ln + 2;
        #pragma unroll
        for (int j = 0; j < 8; ++j) a[j] = sl[a1 + j];
      }
      #pragma unroll
      for (int t = 0; t < 4; ++t)
        acc[cc][t] = __builtin_amdgcn_mfma_f32_16x16x32_f16(bf0[t], a, acc[cc][t], 0, 0, 0);
    }
  }
  // ---- kstep 1: all layer1, slice rr = 2cc + 2 + quad ----
  {
    f16x8 bf[4];
    #pragma unroll
    for (int t = 0; t < 4; ++t)
      bf[t] = *(const f16x8*)(wfrag + (4 + t) * 512);
    #pragma unroll
    for (int cc = 0; cc < 2; ++cc) {
      const int a1 = X1OFF + (2 * cc + 2 + quad) * 48 + 2 * ln + 2;
      f16x8 a;
      #pragma unroll
      for (int j = 0; j < 8; ++j) a[j] = sl[a1 + j];
      #pragma unroll
      for (int t = 0; t < 4; ++t)
        acc[cc][t] = __builtin_amdgcn_mfma_f32_16x16x32_f16(bf[t], a, acc[cc][t], 0, 0, 0);
    }
  }
  // ---- ksteps 2..7: layer2, slice rr = 4cc + 2(s-2) + (quad>>1) ----
  #pragma unroll 3
  for (int s = 2; s < 8; ++s) {
    f16x8 bf[4];
    #pragma unroll
    for (int t = 0; t < 4; ++t)
      bf[t] = *(const f16x8*)(wfrag + (s * 4 + t) * 512);
    #pragma unroll
    for (int cc = 0; cc < 2; ++cc) {
      const int b2 = X2OFF + (4 * cc + 2 * (s - 2) + (quad >> 1)) * 92 + 4 * ln + 4 + 8 * (quad & 1);
      f16x4 lo = *(const f16x4*)&sl[b2];
      f16x4 hi = *(const f16x4*)&sl[b2 + 4];
      f16x8 a;
      a[0] = lo[0]; a[1] = lo[1]; a[2] = lo[2]; a[3] = lo[3];
      a[4] = hi[0]; a[5] = hi[1]; a[6] = hi[2]; a[7] = hi[3];
      #pragma unroll
      for (int t = 0; t < 4; ++t)
        acc[cc][t] = __builtin_amdgcn_mfma_f32_16x16x32_f16(bf[t], a, acc[cc][t], 0, 0, 0);
    }
  }

  // ---- epilogue: fully in-register softmax + direct coalesced stores ----
  const int gx8 = (tx * 16 + ln) * 8;
  #pragma unroll
  for (int cc = 0; cc < 2; ++cc) {
    float v[4][4];
    float m = 0.f;                       // logits are post-ReLU, so >= 0
    #pragma unroll
    for (int t = 0; t < 4; ++t)
      #pragma unroll
      for (int r = 0; r < 4; ++r) {
        float x = fmaxf(acc[cc][t][r], 0.f);
        v[t][r] = x;
        m = fmaxf(m, x);
      }
    m = fmaxf(m, __shfl_xor(m, 16));
    m = fmaxf(m, __shfl_xor(m, 32));

    float sden = 0.f;
    #pragma unroll
    for (int t = 0; t < 4; ++t)
      #pragma unroll
      for (int r = 0; r < 4; ++r) {
        float e = exp2f((v[t][r] - m) * LOG2E);
        v[t][r] = e;
        sden += e;
      }
    sden += __shfl_xor(sden, 16);
    sden += __shfl_xor(sden, 32);

    // rcp (1-ulp) instead of precise divide: absmax is f16-quantization bound.
    const float sc = xs[cc] * __builtin_amdgcn_rcpf(sden);
    const int gy = ty8 * 8 + 2 * wid + cc;
    // chan = 16t + 4*quad + r -> addr = (gy*8 + 2t + (quad>>1))*512 + gx*8 + 4*(quad&1) + r
    float* op = out + nb * 262144 + (gy * 8 + (quad >> 1)) * 512 + gx8 + 4 * (quad & 1);
    #pragma unroll
    for (int t = 0; t < 4; ++t) {
      f32x4 w;
      w[0] = v[t][0] * sc; w[1] = v[t][1] * sc;
      w[2] = v[t][2] * sc; w[3] = v[t][3] * sc;
      *(f32x4*)(op + t * 1024) = w;      // regular store: through L2
    }
  }
}

extern "C" void kernel_launch(void* const* d_in, const int* in_sizes, int n_in,
                              void* d_out, int out_size, void* d_ws, size_t ws_size,
                              hipStream_t stream) {
  const float* x0 = (const float*)d_in[0];
  const float* x1 = (const float*)d_in[1];
  const float* x2 = (const float*)d_in[2];
  const float* W  = (const float*)d_in[3];
  float* outp     = (float*)d_out;
  f16* Wt         = (f16*)d_ws;   // 2048 fragments * 16 B = 32 KB

  prep_wt<<<dim3(8), dim3(256), 0, stream>>>(W, Wt);
  fuse_kernel<<<dim3(2048), dim3(256), 0, stream>>>(x0, x1, x2, Wt, outp);
}